// Round 5
// baseline (4102.985 us; speedup 1.0000x reference)
//
#include <hip/hip_runtime.h>
#include <cstdint>
#include <cstddef>

// RNNQNetwork: MLP encoder (bf16 MFMA GEMMs) -> 128-step GRU scan -> head GEMM.
//
// R5 k_gru: 32 blocks (one per 16-col chunk) x 4 waves; each wave owns TWO
// independent 64-row group-chains (g=wave, wave+4) and alternates between
// them, so one chain's cross-CU handoff (store->L3, flag, poll, h load ~1.5us)
// is hidden under the other chain's compute (~0.9us/slot). Waves never
// interact: per-wave vmcnt drain + per-wave flag publish (no __syncthreads).
// Drain+publish for the previous slot is deferred until after the next slot's
// MFMA, when the stores are ~1 slot old and the drain is free.
// Cross-XCD correctness: h and flags via sc0 sc1 per-access coherent ops
// (R4-proven); h consumer reads are normal cached loads from per-step fresh
// regions (first touch after flag confirm => no stale lines).

#define TT 128
#define BBATCH 512
#define HH 512
#define MM 65536   // T*B
#define AD 18

typedef __attribute__((ext_vector_type(8))) short short8;
typedef __attribute__((ext_vector_type(4))) float float4v;
typedef __attribute__((ext_vector_type(4))) unsigned int uint4v;

__device__ __forceinline__ unsigned short f2bf(float f) {
  union { float f; unsigned int u; } v; v.f = f;
  unsigned int r = v.u + 0x7fffu + ((v.u >> 16) & 1u);  // RNE
  return (unsigned short)(r >> 16);
}
__device__ __forceinline__ float bf2f(unsigned short h) {
  union { unsigned int u; float f; } v; v.u = ((unsigned int)h) << 16;
  return v.f;
}

// per-access coherent (coherence-point) ops: sc0 sc1 = device-scope, no fence
__device__ __forceinline__ unsigned int load_u32_coh(const unsigned int* p) {
  unsigned int v;
  asm volatile("global_load_dword %0, %1, off sc0 sc1\n\ts_waitcnt vmcnt(0)"
               : "=v"(v) : "v"(p) : "memory");
  return v;
}
__device__ __forceinline__ void store_u32_coh(unsigned int* p, unsigned int v) {
  asm volatile("global_store_dword %0, %1, off sc0 sc1"
               :: "v"(p), "v"(v) : "memory");
}
__device__ __forceinline__ void store_u16_coh(unsigned short* p, unsigned int v) {
  asm volatile("global_store_short %0, %1, off sc0 sc1"
               :: "v"(p), "v"(v) : "memory");
}
__device__ __forceinline__ void drain_vmem() {
  asm volatile("s_waitcnt vmcnt(0)" ::: "memory");
}

// async global->LDS, 16B per lane. LDS dest must be wave-uniform base;
// lanes deposit at base + lane*16 (guide section 5 caveat).
typedef __attribute__((address_space(3))) unsigned int* lds_u32p;
typedef const __attribute__((address_space(1))) unsigned int* glb_u32p;
__device__ __forceinline__ void async16(void* lds, const void* g) {
  __builtin_amdgcn_global_load_lds(
      (glb_u32p)(unsigned long long)g,
      (lds_u32p)(unsigned int)(unsigned long long)lds, 16, 0, 0);
}

// ---------------- prep kernels ----------------

// obs fp32 -> bf16 (packed 4/thread); also zero the dones-format flag.
__global__ __launch_bounds__(256) void k_conv_obs(
    const float* __restrict__ src, unsigned short* __restrict__ dst,
    unsigned int* __restrict__ flag) {
  if (blockIdx.x == 0 && threadIdx.x == 0) *flag = 0u;
  int i = blockIdx.x * 256 + threadIdx.x;      // grid sized exactly
  float4v v = ((const float4v*)src)[i];
  unsigned long long pk = (unsigned long long)f2bf(v[0])
      | ((unsigned long long)f2bf(v[1]) << 16)
      | ((unsigned long long)f2bf(v[2]) << 32)
      | ((unsigned long long)f2bf(v[3]) << 48);
  ((unsigned long long*)dst)[i] = pk;
}

// Transpose [512][512] fp32 weights -> [N][K] bf16 (B^T layout for gemm_bt).
// z: 0=w0(first 512 rows), 1=w1, 2=w_ir, 3=w_iz, 4=w_in (into Wi_t slabs).
__global__ __launch_bounds__(256) void k_prep_t(
    const float* __restrict__ w0, const float* __restrict__ w1,
    const float* __restrict__ wir, const float* __restrict__ wiz,
    const float* __restrict__ win,
    unsigned short* __restrict__ W0at, unsigned short* __restrict__ W1t,
    unsigned short* __restrict__ Wit) {
  int o = blockIdx.x * 256 + threadIdx.x;  // o = n*512 + k
  int n = o >> 9, k = o & 511;
  int z = blockIdx.y;
  const float* s = (z == 0) ? w0 : (z == 1) ? w1 : (z == 2) ? wir
                 : (z == 3) ? wiz : win;
  unsigned short b = f2bf(s[k * 512 + n]);
  if (z == 0) W0at[o] = b;
  else if (z == 1) W1t[o] = b;
  else Wit[(size_t)(z - 2) * 262144 + o] = b;
}

// Hidden weights [w_hr|w_hz|w_hn] -> MFMA-B-fragment layout:
// Whf unit (k>>3)*1536 + n holds bf16 W[k0..k0+8][n] contiguously (16B).
__global__ __launch_bounds__(256) void k_prep_whf(
    const float* __restrict__ whr, const float* __restrict__ whz,
    const float* __restrict__ whn, unsigned short* __restrict__ Whf) {
  int i = blockIdx.x * 256 + threadIdx.x;  // < 512*1536, grid exact
  int k = i / 1536, n = i - k * 1536;
  const float* s = (n < 512) ? whr : (n < 1024) ? whz : whn;
  float v = s[k * 512 + (n & 511)];
  Whf[((size_t)(k >> 3) * 1536 + n) * 8 + (k & 7)] = f2bf(v);
}

// Misc: w0 action rows (bf16), combined gru-input bias, w_out^T padded to 64,
// initial h (bf16), zero barrier flags, detect dones dtype.
__global__ __launch_bounds__(256) void k_prep_misc(
    const float* __restrict__ w0, const float* __restrict__ bir,
    const float* __restrict__ biz, const float* __restrict__ bin,
    const float* __restrict__ wout, const float* __restrict__ hidden,
    const int* __restrict__ dI,
    unsigned short* __restrict__ w0act, float* __restrict__ gib,
    unsigned short* __restrict__ WoutT, unsigned short* __restrict__ hbuf,
    unsigned int* __restrict__ ready, unsigned int* __restrict__ flag) {
  int i = blockIdx.x * 256 + threadIdx.x;  // grid 1024 -> i < 262144
  if (i < 9216) {
    int a = i >> 9, n = i & 511;
    w0act[i] = f2bf(w0[(512 + a) * 512 + n]);
  }
  if (i < 1536)
    gib[i] = (i < 512) ? bir[i] : (i < 1024) ? biz[i - 512] : bin[i - 1024];
  if (i < 32768) {
    int n = i >> 9, k = i & 511;
    WoutT[i] = f2bf(n < AD ? wout[k * AD + n] : 0.f);
  }
  if (i < 262144) hbuf[i] = f2bf(hidden[i]);
  if (i < 33280) ready[i] = 0u;  // 8 groups x 130 steps x 32 producers
  // dones dtype probe: first 64KB viewed as int32. int32 bools are only
  // {0,1}; packed byte-bools produce values with bits above bit0.
  if (i < 16384) { if (dI[i] & 0xFFFFFFFE) atomicOr(flag, 1u); }
}

// ---------------- phase A: GEMM C = A @ B^T (+bias [+one-hot gather]) ------

template <int MODE>  // MODE 1: add gathered w0 action row (GEMM1)
__global__ __launch_bounds__(256) void k_gemm_bt(
    const unsigned short* __restrict__ Ab,   // [M][512] bf16
    const unsigned short* __restrict__ Btb,  // [N][512] bf16
    unsigned short* __restrict__ Cb,         // [M][Ndim] bf16
    int Ndim, const float* __restrict__ bias,
    const unsigned short* __restrict__ gW,   // [18][512] bf16
    const int* __restrict__ acts) {
  // chunk-major LDS tiles: unit u = chunk*128 + row, 16B per unit (8 bf16 of k)
  __shared__ unsigned short As[4096];
  __shared__ unsigned short Bs[4096];
  const int tid = threadIdx.x, wave = tid >> 6, lane = tid & 63;
  const int quad = lane >> 4, l15 = lane & 15;
  const int m0 = blockIdx.x * 128, n0 = blockIdx.y * 128;
  const int mblk = (wave & 1) * 64, nblk = (wave >> 1) * 64;

  float4v acc[4][4];
#pragma unroll
  for (int a = 0; a < 4; ++a)
#pragma unroll
    for (int b = 0; b < 4; ++b) acc[a][b] = (float4v){0.f, 0.f, 0.f, 0.f};

  for (int k0 = 0; k0 < 512; k0 += 32) {
#pragma unroll
    for (int r = 0; r < 2; ++r) {
      int u = r * 256 + wave * 64 + lane;
      int ch = u >> 7, mm = u & 127;
      async16(&As[(size_t)(r * 256 + wave * 64) * 8],
              Ab + (size_t)(m0 + mm) * 512 + k0 + ch * 8);
      async16(&Bs[(size_t)(r * 256 + wave * 64) * 8],
              Btb + (size_t)(n0 + mm) * 512 + k0 + ch * 8);
    }
    __syncthreads();  // compiler drains vmcnt before s_barrier
    short8 afr[4], bfr[4];
#pragma unroll
    for (int mi = 0; mi < 4; ++mi)
      afr[mi] = *(const short8*)&As[((quad << 7) + mblk + mi * 16 + l15) * 8];
#pragma unroll
    for (int ni = 0; ni < 4; ++ni)
      bfr[ni] = *(const short8*)&Bs[((quad << 7) + nblk + ni * 16 + l15) * 8];
#pragma unroll
    for (int mi = 0; mi < 4; ++mi)
#pragma unroll
      for (int ni = 0; ni < 4; ++ni)
        acc[mi][ni] = __builtin_amdgcn_mfma_f32_16x16x32_bf16(
            afr[mi], bfr[ni], acc[mi][ni], 0, 0, 0);
    __syncthreads();
  }

#pragma unroll
  for (int mi = 0; mi < 4; ++mi) {
#pragma unroll
    for (int i = 0; i < 4; ++i) {
      int row = m0 + mblk + mi * 16 + quad * 4 + i;
      int arow = (MODE == 1) ? acts[row] : 0;
#pragma unroll
      for (int ni = 0; ni < 4; ++ni) {
        int col = n0 + nblk + ni * 16 + l15;
        float v = acc[mi][ni][i] + bias[col];
        if (MODE == 1) v += bf2f(gW[arow * 512 + col]);
        Cb[(size_t)row * Ndim + col] = f2bf(v);
      }
    }
  }
}

// ---------------- LayerNorm(+bias already applied) + ReLU, bf16->bf16 -------

__global__ __launch_bounds__(256) void k_ln_relu(
    const unsigned short* __restrict__ X, unsigned short* __restrict__ Y,
    const float* __restrict__ sc, const float* __restrict__ bi) {
  int row = blockIdx.x * 4 + (threadIdx.x >> 6);  // one wave per row
  int lane = threadIdx.x & 63;
  uint4v u = *(const uint4v*)(X + (size_t)row * 512 + lane * 8);
  float v[8];
#pragma unroll
  for (int j = 0; j < 4; ++j) {
    v[2 * j] = bf2f((unsigned short)(u[j] & 0xffffu));
    v[2 * j + 1] = bf2f((unsigned short)(u[j] >> 16));
  }
  float s = 0.f, q = 0.f;
#pragma unroll
  for (int j = 0; j < 8; ++j) { s += v[j]; q += v[j] * v[j]; }
#pragma unroll
  for (int d = 1; d < 64; d <<= 1) {
    s += __shfl_xor(s, d, 64);
    q += __shfl_xor(q, d, 64);
  }
  float mean = s * (1.f / 512.f);
  float var = fmaxf(q * (1.f / 512.f) - mean * mean, 0.f);
  float rstd = rsqrtf(var + 1e-6f);
  float4v s0 = *(const float4v*)(sc + lane * 8);
  float4v s1 = *(const float4v*)(sc + lane * 8 + 4);
  float4v c0 = *(const float4v*)(bi + lane * 8);
  float4v c1 = *(const float4v*)(bi + lane * 8 + 4);
  uint4v w;
#pragma unroll
  for (int j = 0; j < 4; ++j) {
    float a0 = fmaxf((v[2 * j] - mean) * rstd * (j < 2 ? s0[2 * j] : s1[2 * j - 4])
                         + (j < 2 ? c0[2 * j] : c1[2 * j - 4]), 0.f);
    float a1 = fmaxf((v[2 * j + 1] - mean) * rstd
                         * (j < 2 ? s0[2 * j + 1] : s1[2 * j - 3])
                         + (j < 2 ? c0[2 * j + 1] : c1[2 * j - 3]), 0.f);
    w[j] = (unsigned int)f2bf(a0) | ((unsigned int)f2bf(a1) << 16);
  }
  *(uint4v*)(Y + (size_t)row * 512 + lane * 8) = w;
}

// ---------------- phase B: GRU scan -----------------------------------------
// 32 blocks (one per 16-col chunk) x 4 waves. Wave w owns chains g=w and
// g=w+4 (64 rows each) and alternates slots between them each step.
// No __syncthreads: per-wave vmcnt drain orders h stores before flag publish;
// the drain+publish of slot S-1 happens after slot S's MFMA (stores are old,
// drain ~free). Flags: ready[(g*130+t)*32+cc], sc0sc1 stores/poll loads.

__global__ __launch_bounds__(256, 1) void k_gru(
    const unsigned short* __restrict__ Whf, const unsigned short* __restrict__ gin,
    const float* __restrict__ bhn, const int* __restrict__ dI,
    const unsigned char* __restrict__ dB, const unsigned int* __restrict__ flag,
    const unsigned short* __restrict__ hbuf, unsigned short* __restrict__ ybuf,
    float* __restrict__ outh, unsigned int* __restrict__ ready) {
  const int tid = threadIdx.x, wave = tid >> 6, lane = tid & 63;
  const int quad = lane >> 4, l15 = lane & 15;
  const int cc = blockIdx.x;        // 0..31 col chunk
  const int col = cc * 16 + l15;
  const int bytemode = (int)(*flag);
  const float bhn_c = bhn[col];

  // weight-stationary B fragments: [gate][k-step] (shared by both chains)
  short8 bw[3][16];
#pragma unroll
  for (int kc = 0; kc < 16; ++kc)
#pragma unroll
    for (int g = 0; g < 3; ++g) {
      size_t u = (size_t)(kc * 4 + quad) * 1536 + (g * 512 + col);
      bw[g][kc] = *(const short8*)(Whf + u * 8);
    }

  // own h carried in registers per chain: [slot][tile*4+i]
  float hold[2][16];
#pragma unroll
  for (int s = 0; s < 2; ++s) {
    int g = wave + s * 4;
#pragma unroll
    for (int tile = 0; tile < 4; ++tile)
#pragma unroll
      for (int i = 0; i < 4; ++i) {
        int row = g * 64 + tile * 16 + quad * 4 + i;
        hold[s][tile * 4 + i] = bf2f(hbuf[(size_t)row * 512 + col]);
      }
  }

  int pg = -1, pt = 0;  // previous slot (pending flag publish)
  for (int t = 0; t < TT; ++t) {
#pragma unroll
    for (int s = 0; s < 2; ++s) {
      const int g = wave + s * 4;
      if (t > 0) {
        // all 64 lanes poll the 32 per-producer flags (lane&31) in parallel
        const unsigned int* fp =
            ready + ((size_t)g * 130 + t) * 32 + (lane & 31);
        unsigned int v;
        int guard = 0;
        do {
          v = load_u32_coh(fp);
        } while (__ballot(v == 0u) != 0ull && ++guard < (1 << 20));
      }
      const unsigned short* hsrc =
          (t == 0) ? hbuf : ybuf + (size_t)(t - 1) * 262144;
      unsigned short* ydst = ybuf + (size_t)t * 262144;
      const unsigned short* gbase = gin + (size_t)t * 512 * 1536;

#pragma unroll
      for (int tile = 0; tile < 4; ++tile) {
        const int rowA = g * 64 + tile * 16 + l15;
        int dA = bytemode ? (int)dB[t * 512 + rowA] : dI[t * 512 + rowA];
        const unsigned short* ap = hsrc + (size_t)rowA * 512 + quad * 8;
        short8 af[16];
#pragma unroll
        for (int kc = 0; kc < 16; ++kc) af[kc] = *(const short8*)(ap + kc * 32);
        if (dA) {
          const short8 z8 = {0, 0, 0, 0, 0, 0, 0, 0};
#pragma unroll
          for (int kc = 0; kc < 16; ++kc) af[kc] = z8;
        }
        // epilogue operands for this tile
        float ginr[4], ginz[4], ginn[4];
        int dd[4];
#pragma unroll
        for (int i = 0; i < 4; ++i) {
          int row = g * 64 + tile * 16 + quad * 4 + i;
          dd[i] = bytemode ? (int)dB[t * 512 + row] : dI[t * 512 + row];
          ginr[i] = bf2f(gbase[(size_t)row * 1536 + col]);
          ginz[i] = bf2f(gbase[(size_t)row * 1536 + 512 + col]);
          ginn[i] = bf2f(gbase[(size_t)row * 1536 + 1024 + col]);
        }

        float4v a0 = {0.f, 0.f, 0.f, 0.f}, a1 = a0, a2 = a0;
#pragma unroll
        for (int kc = 0; kc < 16; ++kc) {
          a0 = __builtin_amdgcn_mfma_f32_16x16x32_bf16(af[kc], bw[0][kc], a0, 0, 0, 0);
          a1 = __builtin_amdgcn_mfma_f32_16x16x32_bf16(af[kc], bw[1][kc], a1, 0, 0, 0);
          a2 = __builtin_amdgcn_mfma_f32_16x16x32_bf16(af[kc], bw[2][kc], a2, 0, 0, 0);
        }

        if (tile == 0) {
          // previous slot's h stores are ~1 slot old: drain is ~free.
          drain_vmem();
          if (pg >= 0 && lane == 0)
            store_u32_coh(&ready[((size_t)pg * 130 + pt + 1) * 32 + cc], 1u);
        }

#pragma unroll
        for (int i = 0; i < 4; ++i) {
          int row = g * 64 + tile * 16 + quad * 4 + i;
          float holdv = dd[i] ? 0.f : hold[s][tile * 4 + i];
          float r = 1.f / (1.f + __expf(-(a0[i] + ginr[i])));
          float z = 1.f / (1.f + __expf(-(a1[i] + ginz[i])));
          float npre = ginn[i] + r * (a2[i] + bhn_c);
          float n = 1.f - 2.f / (1.f + __expf(2.f * npre));  // tanh, inf-safe
          float hnew = (1.f - z) * n + z * holdv;
          hold[s][tile * 4 + i] = hnew;
          // write-through to coherence point: next step's cross-XCD input
          store_u16_coh(ydst + (size_t)row * 512 + col,
                        (unsigned int)f2bf(hnew));
          if (t == TT - 1) outh[(size_t)row * 512 + col] = hnew;
        }
      }
      pg = g; pt = t;
    }
  }
}

// ---------------- phase C: q = y @ w_out + b_out (N padded to 64) -----------

__global__ __launch_bounds__(256) void k_qout(
    const unsigned short* __restrict__ Yb, const unsigned short* __restrict__ Wt,
    const float* __restrict__ bout, float* __restrict__ Q) {
  __shared__ unsigned short As[4096];
  __shared__ unsigned short Bs[2048];
  const int tid = threadIdx.x, wave = tid >> 6, lane = tid & 63;
  const int quad = lane >> 4, l15 = lane & 15;
  const int m0 = blockIdx.x * 128;

  float4v acc[2][4];
#pragma unroll
  for (int a = 0; a < 2; ++a)
#pragma unroll
    for (int b = 0; b < 4; ++b) acc[a][b] = (float4v){0.f, 0.f, 0.f, 0.f};

  for (int k0 = 0; k0 < 512; k0 += 32) {
#pragma unroll
    for (int r = 0; r < 2; ++r) {
      int u = r * 256 + wave * 64 + lane;
      int ch = u >> 7, mm = u & 127;
      async16(&As[(size_t)(r * 256 + wave * 64) * 8],
              Yb + (size_t)(m0 + mm) * 512 + k0 + ch * 8);
    }
    {
      int u = wave * 64 + lane;
      int ch = u >> 6, nn = u & 63;
      async16(&Bs[(size_t)(wave * 64) * 8], Wt + (size_t)nn * 512 + k0 + ch * 8);
    }
    __syncthreads();
    short8 afr[2], bfr[4];
#pragma unroll
    for (int mi = 0; mi < 2; ++mi)
      afr[mi] = *(const short8*)&As[((quad << 7) + wave * 32 + mi * 16 + l15) * 8];
#pragma unroll
    for (int ni = 0; ni < 4; ++ni)
      bfr[ni] = *(const short8*)&Bs[((quad << 6) + ni * 16 + l15) * 8];
#pragma unroll
    for (int mi = 0; mi < 2; ++mi)
#pragma unroll
      for (int ni = 0; ni < 4; ++ni)
        acc[mi][ni] = __builtin_amdgcn_mfma_f32_16x16x32_bf16(
            afr[mi], bfr[ni], acc[mi][ni], 0, 0, 0);
    __syncthreads();
  }
#pragma unroll
  for (int mi = 0; mi < 2; ++mi)
#pragma unroll
    for (int ni = 0; ni < 4; ++ni)
#pragma unroll
      for (int i = 0; i < 4; ++i) {
        int row = m0 + wave * 32 + mi * 16 + quad * 4 + i;
        int colq = ni * 16 + l15;
        if (colq < AD) Q[(size_t)row * AD + colq] = acc[mi][ni][i] + bout[colq];
      }
}

// ---------------- launch ----------------------------------------------------

extern "C" void kernel_launch(void* const* d_in, const int* in_sizes, int n_in,
                              void* d_out, int out_size, void* d_ws,
                              size_t ws_size, hipStream_t stream) {
  const float* hidden = (const float*)d_in[0];
  const float* obs = (const float*)d_in[1];
  const void* dones = d_in[2];
  const int* acts = (const int*)d_in[3];
  const float* w0 = (const float*)d_in[4];
  const float* b0 = (const float*)d_in[5];
  const float* ln0s = (const float*)d_in[6];
  const float* ln0b = (const float*)d_in[7];
  const float* w1 = (const float*)d_in[8];
  const float* b1 = (const float*)d_in[9];
  const float* ln1s = (const float*)d_in[10];
  const float* ln1b = (const float*)d_in[11];
  const float* wir = (const float*)d_in[12];
  const float* bir = (const float*)d_in[13];
  const float* wiz = (const float*)d_in[14];
  const float* biz = (const float*)d_in[15];
  const float* win = (const float*)d_in[16];
  const float* bin = (const float*)d_in[17];
  const float* whr = (const float*)d_in[18];
  const float* whz = (const float*)d_in[19];
  const float* whn = (const float*)d_in[20];
  const float* bhn = (const float*)d_in[21];
  const float* wout = (const float*)d_in[22];
  const float* bout = (const float*)d_in[23];

  char* ws = (char*)d_ws;
  unsigned short* bufA = (unsigned short*)(ws);                   // 64MB: obs_bf -> x1 -> x2
  unsigned short* bufB = (unsigned short*)(ws + 67108864ULL);     // 64MB: pre0 -> pre1 -> y/h
  unsigned short* gin = (unsigned short*)(ws + 134217728ULL);     // 192MB
  char* D = ws + 134217728ULL + 201326592ULL;
  unsigned short* W0at = (unsigned short*)(D);                    // 512KB
  unsigned short* W1t = (unsigned short*)(D + 524288);            // 512KB
  unsigned short* Wit = (unsigned short*)(D + 1048576);           // 1.5MB
  unsigned short* Whf = (unsigned short*)(D + 2621440);           // 1.5MB
  unsigned short* WoutT = (unsigned short*)(D + 4194304);         // 64KB
  unsigned short* w0act = (unsigned short*)(D + 4259840);         // 32KB
  float* gib = (float*)(D + 4292608);                             // 8KB
  unsigned short* hbuf = (unsigned short*)(D + 4300800);          // 512KB init h
  unsigned int* ready = (unsigned int*)(D + 5349376);             // 133KB flags
  unsigned int* flag = ready + 33280;

  (void)in_sizes; (void)n_in; (void)out_size; (void)ws_size;

  k_conv_obs<<<32768, 256, 0, stream>>>(obs, bufA, flag);
  k_prep_t<<<dim3(1024, 5), 256, 0, stream>>>(w0, w1, wir, wiz, win, W0at, W1t, Wit);
  k_prep_whf<<<3072, 256, 0, stream>>>(whr, whz, whn, Whf);
  k_prep_misc<<<1024, 256, 0, stream>>>(w0, bir, biz, bin, wout, hidden,
                                        (const int*)dones, w0act, gib, WoutT,
                                        hbuf, ready, flag);
  // encoder
  k_gemm_bt<1><<<dim3(512, 4), 256, 0, stream>>>(bufA, W0at, bufB, 512, b0, w0act, acts);
  k_ln_relu<<<16384, 256, 0, stream>>>(bufB, bufA, ln0s, ln0b);
  k_gemm_bt<0><<<dim3(512, 4), 256, 0, stream>>>(bufA, W1t, bufB, 512, b1, nullptr, nullptr);
  k_ln_relu<<<16384, 256, 0, stream>>>(bufB, bufA, ln1s, ln1b);
  // GRU input projections (biases fused)
  k_gemm_bt<0><<<dim3(512, 12), 256, 0, stream>>>(bufA, Wit, gin, 1536, gib, nullptr, nullptr);
  // sequential scan; writes new_hidden to d_out[0:262144] and y/h to bufB
  k_gru<<<32, 256, 0, stream>>>(Whf, gin, bhn, (const int*)dones,
                                (const unsigned char*)dones, flag, hbuf, bufB,
                                (float*)d_out, ready);
  // output head -> d_out[262144:]
  k_qout<<<512, 256, 0, stream>>>(bufB, WoutT, bout, (float*)d_out + 262144);
}